// Round 3
// baseline (518.240 us; speedup 1.0000x reference)
//
#include <hip/hip_runtime.h>
#include <cstdint>

constexpr int BTOT = 1048576;
constexpr int LCLS = 81;
constexpr int GRP  = 9;
constexpr int THR  = 256;                 // threads per block == rows per block
constexpr int NBLK = BTOT / THR;          // 4096
constexpr int TILE4 = THR * LCLS / 4;     // 5184 float4 per block tile
constexpr float FIX = 67108864.0f;        // 2^26 fixed-point scale for loss

// Rare knife-edge path (~1e-5 of rows): recompute group argmax in f64 from
// global (rows are L2-hot). First-max-wins via strict >.
__device__ __attribute__((noinline)) int refine_group_f64(const float* __restrict__ xrow)
{
    double best = -1.0; int bi = 0;
    #pragma unroll
    for (int g = 0; g < GRP; ++g) {
        double s = 0.0;
        #pragma unroll
        for (int j = 0; j < GRP; ++j) s += exp((double)xrow[g * GRP + j]);
        if (s > best) { best = s; bi = g; }
    }
    return bi;
}

__global__ __launch_bounds__(THR) void hl_main(
    const float* __restrict__ x, const int* __restrict__ tgt,
    float* __restrict__ out, unsigned long long* __restrict__ part)
{
    __shared__ float gs[THR * GRP];           // 9,216 B: per-row group exp-sums
    const int tid = threadIdx.x;

    #pragma unroll
    for (int i = tid; i < THR * GRP; i += THR) gs[i] = 0.0f;
    __syncthreads();

    const size_t tbase = (size_t)blockIdx.x * (THR * LCLS);
    const float4* g4 = reinterpret_cast<const float4*>(x + tbase);

    // ---- pass 1: coalesced float4 stream; scatter exp into LDS group sums ----
    for (int i = tid; i < TILE4; i += THR) {
        float4 v = g4[i];
        unsigned e = 4u * (unsigned)i;
        {   unsigned r = e / 81u, j = e - r * 81u, g = j / 9u;
            atomicAdd(&gs[r * GRP + g], __expf(v.x)); }
        {   unsigned e1 = e + 1, r = e1 / 81u, j = e1 - r * 81u, g = j / 9u;
            atomicAdd(&gs[r * GRP + g], __expf(v.y)); }
        {   unsigned e2 = e + 2, r = e2 / 81u, j = e2 - r * 81u, g = j / 9u;
            atomicAdd(&gs[r * GRP + g], __expf(v.z)); }
        {   unsigned e3 = e + 3, r = e3 / 81u, j = e3 - r * 81u, g = j / 9u;
            atomicAdd(&gs[r * GRP + g], __expf(v.w)); }
    }
    __syncthreads();

    // ---- pass 2: one row per thread ----
    const int row = blockIdx.x * THR + tid;
    float gsr[GRP];
    #pragma unroll
    for (int g = 0; g < GRP; ++g) gsr[g] = gs[tid * GRP + g];

    float S = gsr[0];
    #pragma unroll
    for (int g = 1; g < GRP; ++g) S += gsr[g];

    // group argmax, top-2 tracked (strict >, first index wins)
    float g1 = gsr[0], g2 = -1e30f; int gi = 0;
    #pragma unroll
    for (int g = 1; g < GRP; ++g) {
        float v = gsr[g];
        bool gt = v > g1;
        g2 = gt ? g1 : (v > g2 ? v : g2);
        g1 = gt ? v  : g1;
        gi = gt ? g  : gi;
    }

    const int t = tgt[row];
    const int parent = t / GRP;

    float gpar = gsr[0];
    #pragma unroll
    for (int g = 1; g < GRP; ++g)
        gpar = (parent == g) ? gsr[g] : gpar;          // static-index select chain

    const float* xrow = x + tbase + tid * LCLS;        // L2-hot (just streamed)

    if (g1 - g2 < 1e-5f * g1) gi = refine_group_f64(xrow);

    // within-group argmax on RAW x — exp is monotonic, so this is EXACT
    const int wb = gi * GRP;
    float w1 = xrow[wb]; int wi = 0;
    #pragma unroll
    for (int j = 1; j < GRP; ++j) {
        float v = xrow[wb + j];
        if (v > w1) { w1 = v; wi = j; }
    }

    const int pred = gi * GRP + wi;

    float et  = expf(xrow[t]);                          // precise ocml exp
    float win = 0.5f * (gpar + et) / S;
    float nl  = -logf(win);
    unsigned long long lq = (unsigned long long)llrintf(nl * FIX);
    int dist = (pred == t) ? 0 : ((gi == parent) ? 1 : 2);

    out[1 + row] = (float)pred;

    // ---- deterministic block reduction: fixed-point loss + int dist ----
    #pragma unroll
    for (int off = 32; off > 0; off >>= 1) {
        lq   += __shfl_down(lq, off);
        dist += __shfl_down(dist, off);
    }
    __shared__ unsigned long long redL[THR / 64];
    __shared__ unsigned long long redD[THR / 64];
    if ((tid & 63) == 0) { redL[tid >> 6] = lq; redD[tid >> 6] = (unsigned long long)(unsigned)dist; }
    __syncthreads();
    if (tid == 0) {
        unsigned long long a = redL[0], b = redD[0];
        #pragma unroll
        for (int w = 1; w < THR / 64; ++w) { a += redL[w]; b += redD[w]; }
        part[blockIdx.x] = a;
        part[NBLK + blockIdx.x] = b;
    }
}

__global__ __launch_bounds__(256) void hl_final(
    const unsigned long long* __restrict__ part, float* __restrict__ out)
{
    const int tid = threadIdx.x;
    unsigned long long a = 0, b = 0;
    for (int i = tid; i < NBLK; i += 256) { a += part[i]; b += part[NBLK + i]; }
    #pragma unroll
    for (int off = 32; off > 0; off >>= 1) { a += __shfl_down(a, off); b += __shfl_down(b, off); }
    __shared__ unsigned long long rA[4], rB[4];
    if ((tid & 63) == 0) { rA[tid >> 6] = a; rB[tid >> 6] = b; }
    __syncthreads();
    if (tid == 0) {
        unsigned long long ta = 0, tb = 0;
        #pragma unroll
        for (int w = 0; w < 4; ++w) { ta += rA[w]; tb += rB[w]; }
        double loss = ((double)ta / 67108864.0) / (double)BTOT;
        out[0] = (float)loss;                  // -mean(log(win))
        out[1 + BTOT] = (float)tb;             // total_dist
    }
}

extern "C" void kernel_launch(void* const* d_in, const int* in_sizes, int n_in,
                              void* d_out, int out_size, void* d_ws, size_t ws_size,
                              hipStream_t stream) {
    const float* outputs = (const float*)d_in[0];
    const int*   target  = (const int*)d_in[1];
    float* out = (float*)d_out;
    unsigned long long* part = (unsigned long long*)d_ws;   // needs 2*4096*8 = 65,536 B

    hl_main<<<NBLK, THR, 0, stream>>>(outputs, target, out, part);
    hl_final<<<1, 256, 0, stream>>>(part, out);
}

// Round 4
// 79.675 us; speedup vs baseline: 6.5044x; 6.5044x over previous
//
#include <hip/hip_runtime.h>
#include <cstdint>

constexpr int BTOT = 1048576;
constexpr int LCLS = 81;
constexpr int GRP  = 9;
constexpr int ROWS = 128;                  // rows per block == threads per block
constexpr int THR  = 128;
constexpr int NBLK = BTOT / ROWS;          // 8192
constexpr int TILE4 = ROWS * LCLS / 4;     // 2592 float4 per tile
constexpr int FULLR = TILE4 / THR;         // 20 full staging rounds
constexpr int TAIL  = TILE4 - FULLR * THR; // 32 leftover float4
constexpr float FIX = 67108864.0f;         // 2^26 fixed-point scale for loss

// Async global->LDS, 16B per lane, no VGPR round-trip. LDS dest is
// readfirstlane(base) + lane*16, which matches lane-consecutive float4s
// into a linear tile (m97 pattern).
__device__ inline void gload_lds16(const float* gsrc, float* ldst) {
    __builtin_amdgcn_global_load_lds(
        (const __attribute__((address_space(1))) void*)gsrc,
        (__attribute__((address_space(3))) void*)ldst,
        16, 0, 0);
}

// Rare knife-edge path (~1e-5 of rows): recompute group argmax in f64 from
// the LDS row. First-max-wins via strict >.
__device__ __attribute__((noinline)) int refine_group_f64(const float* __restrict__ xrow)
{
    double best = -1.0; int bi = 0;
    #pragma unroll
    for (int g = 0; g < GRP; ++g) {
        double s = 0.0;
        #pragma unroll
        for (int j = 0; j < GRP; ++j) s += exp((double)xrow[g * GRP + j]);
        if (s > best) { best = s; bi = g; }
    }
    return bi;
}

__global__ __launch_bounds__(THR) void hl_main(
    const float* __restrict__ x, const int* __restrict__ tgt,
    float* __restrict__ out, unsigned long long* __restrict__ part)
{
    __shared__ float tile[ROWS * LCLS];        // 41,472 B -> 3 blocks/CU
    const int tid = threadIdx.x;
    const size_t tbase = (size_t)blockIdx.x * (ROWS * LCLS);
    const float* gt = x + tbase;               // 16B-aligned (41,472 % 16 == 0)

    // ---- stage: issue ALL tile loads async before waiting (deep burst) ----
    #pragma unroll
    for (int r = 0; r < FULLR; ++r) {
        const int i = r * THR + tid;           // float4 index
        gload_lds16(gt + 4 * i, &tile[4 * i]);
    }
    if (tid < TAIL) {
        const int i = FULLR * THR + tid;
        gload_lds16(gt + 4 * i, &tile[4 * i]);
    }
    __syncthreads();                           // drains vmcnt (incl. load_lds)

    // ---- one row per thread, all reads from LDS ----
    const int row = blockIdx.x * ROWS + tid;
    const float* xr = tile + tid * LCLS;       // stride-81: 2-way bank alias = free

    float gs[GRP];
    #pragma unroll
    for (int g = 0; g < GRP; ++g) {
        float s = 0.0f;
        #pragma unroll
        for (int j = 0; j < GRP; ++j) s += __expf(xr[g * GRP + j]);
        gs[g] = s;
    }
    float S = gs[0];
    #pragma unroll
    for (int g = 1; g < GRP; ++g) S += gs[g];

    // group argmax, top-2 tracked (strict >, first index wins)
    float g1 = gs[0], g2 = -1e30f; int gi = 0;
    #pragma unroll
    for (int g = 1; g < GRP; ++g) {
        float v = gs[g];
        bool gt2 = v > g1;
        g2 = gt2 ? g1 : (v > g2 ? v : g2);
        g1 = gt2 ? v  : g1;
        gi = gt2 ? g  : gi;
    }

    const int t = tgt[row];
    const int parent = t / GRP;

    float gpar = gs[0];
    #pragma unroll
    for (int g = 1; g < GRP; ++g)
        gpar = (parent == g) ? gs[g] : gpar;   // static-index select chain

    if (g1 - g2 < 1e-5f * g1) gi = refine_group_f64(xr);

    // within-group argmax on RAW x — exp/softmax are monotonic, so EXACT
    const int wb = gi * GRP;
    float w1 = xr[wb]; int wi = 0;
    #pragma unroll
    for (int j = 1; j < GRP; ++j) {
        float v = xr[wb + j];
        if (v > w1) { w1 = v; wi = j; }
    }

    const int pred = gi * GRP + wi;

    float et  = expf(xr[t]);                   // precise ocml exp, once per row
    float win = 0.5f * (gpar + et) / S;
    float nl  = -logf(win);
    unsigned long long lq = (unsigned long long)llrintf(nl * FIX);
    int dist = (pred == t) ? 0 : ((gi == parent) ? 1 : 2);

    out[1 + row] = (float)pred;

    // ---- deterministic block reduction: fixed-point loss + int dist ----
    #pragma unroll
    for (int off = 32; off > 0; off >>= 1) {
        lq   += __shfl_down(lq, off);
        dist += __shfl_down(dist, off);
    }
    __shared__ unsigned long long redL[THR / 64];
    __shared__ unsigned long long redD[THR / 64];
    if ((tid & 63) == 0) { redL[tid >> 6] = lq; redD[tid >> 6] = (unsigned long long)(unsigned)dist; }
    __syncthreads();
    if (tid == 0) {
        unsigned long long a = redL[0], b = redD[0];
        #pragma unroll
        for (int w = 1; w < THR / 64; ++w) { a += redL[w]; b += redD[w]; }
        part[blockIdx.x] = a;
        part[NBLK + blockIdx.x] = b;
    }
}

__global__ __launch_bounds__(256) void hl_final(
    const unsigned long long* __restrict__ part, float* __restrict__ out)
{
    const int tid = threadIdx.x;
    unsigned long long a = 0, b = 0;
    for (int i = tid; i < NBLK; i += 256) { a += part[i]; b += part[NBLK + i]; }
    #pragma unroll
    for (int off = 32; off > 0; off >>= 1) { a += __shfl_down(a, off); b += __shfl_down(b, off); }
    __shared__ unsigned long long rA[4], rB[4];
    if ((tid & 63) == 0) { rA[tid >> 6] = a; rB[tid >> 6] = b; }
    __syncthreads();
    if (tid == 0) {
        unsigned long long ta = 0, tb = 0;
        #pragma unroll
        for (int w = 0; w < 4; ++w) { ta += rA[w]; tb += rB[w]; }
        double loss = ((double)ta / 67108864.0) / (double)BTOT;
        out[0] = (float)loss;                  // -mean(log(win))
        out[1 + BTOT] = (float)tb;             // total_dist
    }
}

extern "C" void kernel_launch(void* const* d_in, const int* in_sizes, int n_in,
                              void* d_out, int out_size, void* d_ws, size_t ws_size,
                              hipStream_t stream) {
    const float* outputs = (const float*)d_in[0];
    const int*   target  = (const int*)d_in[1];
    float* out = (float*)d_out;
    unsigned long long* part = (unsigned long long*)d_ws;   // needs 2*8192*8 = 131,072 B

    hl_main<<<NBLK, THR, 0, stream>>>(outputs, target, out, part);
    hl_final<<<1, 256, 0, stream>>>(part, out);
}

// Round 5
// 75.849 us; speedup vs baseline: 6.8326x; 1.0505x over previous
//
#include <hip/hip_runtime.h>
#include <cstdint>

constexpr int BTOT = 1048576;
constexpr int LCLS = 81;
constexpr int GRP  = 9;
constexpr int ROWS = 64;                   // rows per block == threads per block (1 wave)
constexpr int THR  = 64;
constexpr int NBLK = BTOT / ROWS;          // 16384
constexpr int TILE4 = ROWS * LCLS / 4;     // 1296 float4 per tile
constexpr int FULLR = TILE4 / THR;         // 20 full staging rounds
constexpr int TAIL  = TILE4 - FULLR * THR; // 16 leftover float4
constexpr float FIX = 67108864.0f;         // 2^26 fixed-point scale for loss

// Async global->LDS, 16B per lane, no VGPR round-trip (m97 pattern:
// lane-consecutive float4s into a linear LDS tile).
__device__ inline void gload_lds16(const float* gsrc, float* ldst) {
    __builtin_amdgcn_global_load_lds(
        (const __attribute__((address_space(1))) void*)gsrc,
        (__attribute__((address_space(3))) void*)ldst,
        16, 0, 0);
}

// Rare knife-edge path (~1e-5 of rows): recompute group argmax in f64 from
// the LDS row. First-max-wins via strict >.
__device__ __attribute__((noinline)) int refine_group_f64(const float* __restrict__ xrow)
{
    double best = -1.0; int bi = 0;
    #pragma unroll
    for (int g = 0; g < GRP; ++g) {
        double s = 0.0;
        #pragma unroll
        for (int j = 0; j < GRP; ++j) s += exp((double)xrow[g * GRP + j]);
        if (s > best) { best = s; bi = g; }
    }
    return bi;
}

__global__ __launch_bounds__(THR) void hl_main(
    const float* __restrict__ x, const int* __restrict__ tgt,
    float* __restrict__ out, unsigned long long* __restrict__ part)
{
    __shared__ float tile[ROWS * LCLS];        // 20,736 B -> 7 single-wave blocks/CU
    const int tid = threadIdx.x;
    const size_t tbase = (size_t)blockIdx.x * (ROWS * LCLS);
    const float* gt = x + tbase;               // 16B-aligned (20,736 % 16 == 0)

    // ---- stage: issue the whole tile async before waiting (deep burst) ----
    #pragma unroll
    for (int r = 0; r < FULLR; ++r) {
        const int i = r * THR + tid;           // float4 index
        gload_lds16(gt + 4 * i, &tile[4 * i]);
    }
    if (tid < TAIL) {
        const int i = FULLR * THR + tid;
        gload_lds16(gt + 4 * i, &tile[4 * i]);
    }
    __syncthreads();                           // drains vmcnt (1-wave barrier, cheap)

    // ---- one row per thread, all reads from LDS ----
    const int row = blockIdx.x * ROWS + tid;
    const float* xr = tile + tid * LCLS;       // stride-81: 2-way bank alias = free

    float gs[GRP];
    #pragma unroll
    for (int g = 0; g < GRP; ++g) {
        float s = 0.0f;
        #pragma unroll
        for (int j = 0; j < GRP; ++j) s += __expf(xr[g * GRP + j]);
        gs[g] = s;
    }
    float S = gs[0];
    #pragma unroll
    for (int g = 1; g < GRP; ++g) S += gs[g];

    // group argmax, top-2 tracked (strict >, first index wins)
    float g1 = gs[0], g2 = -1e30f; int gi = 0;
    #pragma unroll
    for (int g = 1; g < GRP; ++g) {
        float v = gs[g];
        bool gt2 = v > g1;
        g2 = gt2 ? g1 : (v > g2 ? v : g2);
        g1 = gt2 ? v  : g1;
        gi = gt2 ? g  : gi;
    }

    const int t = tgt[row];
    const int parent = t / GRP;

    float gpar = gs[0];
    #pragma unroll
    for (int g = 1; g < GRP; ++g)
        gpar = (parent == g) ? gs[g] : gpar;   // static-index select chain

    if (g1 - g2 < 1e-5f * g1) gi = refine_group_f64(xr);

    // within-group argmax on RAW x — exp/softmax are monotonic, so EXACT
    const int wb = gi * GRP;
    float w1 = xr[wb]; int wi = 0;
    #pragma unroll
    for (int j = 1; j < GRP; ++j) {
        float v = xr[wb + j];
        if (v > w1) { w1 = v; wi = j; }
    }

    const int pred = gi * GRP + wi;

    float et  = expf(xr[t]);                   // precise ocml exp, once per row
    float win = 0.5f * (gpar + et) / S;
    float nl  = -logf(win);
    unsigned long long lq = (unsigned long long)llrintf(nl * FIX);
    int dist = (pred == t) ? 0 : ((gi == parent) ? 1 : 2);

    out[1 + row] = (float)pred;

    // ---- deterministic single-wave reduction: fixed-point loss + int dist ----
    #pragma unroll
    for (int off = 32; off > 0; off >>= 1) {
        lq   += __shfl_down(lq, off);
        dist += __shfl_down(dist, off);
    }
    if (tid == 0) {
        part[blockIdx.x] = lq;
        part[NBLK + blockIdx.x] = (unsigned long long)(unsigned)dist;
    }
}

__global__ __launch_bounds__(1024) void hl_final(
    const unsigned long long* __restrict__ part, float* __restrict__ out)
{
    const int tid = threadIdx.x;
    unsigned long long a = 0, b = 0;
    for (int i = tid; i < NBLK; i += 1024) { a += part[i]; b += part[NBLK + i]; }
    #pragma unroll
    for (int off = 32; off > 0; off >>= 1) { a += __shfl_down(a, off); b += __shfl_down(b, off); }
    __shared__ unsigned long long rA[16], rB[16];
    if ((tid & 63) == 0) { rA[tid >> 6] = a; rB[tid >> 6] = b; }
    __syncthreads();
    if (tid == 0) {
        unsigned long long ta = 0, tb = 0;
        #pragma unroll
        for (int w = 0; w < 16; ++w) { ta += rA[w]; tb += rB[w]; }
        double loss = ((double)ta / 67108864.0) / (double)BTOT;
        out[0] = (float)loss;                  // -mean(log(win))
        out[1 + BTOT] = (float)tb;             // total_dist
    }
}

extern "C" void kernel_launch(void* const* d_in, const int* in_sizes, int n_in,
                              void* d_out, int out_size, void* d_ws, size_t ws_size,
                              hipStream_t stream) {
    const float* outputs = (const float*)d_in[0];
    const int*   target  = (const int*)d_in[1];
    float* out = (float*)d_out;
    unsigned long long* part = (unsigned long long*)d_ws;   // needs 2*16384*8 = 262,144 B

    hl_main<<<NBLK, THR, 0, stream>>>(outputs, target, out, part);
    hl_final<<<1, 1024, 0, stream>>>(part, out);
}